// Round 7
// baseline (250.880 us; speedup 1.0000x reference)
//
#include <hip/hip_runtime.h>

typedef __bf16 bf16_t;
typedef bf16_t bf16x8 __attribute__((ext_vector_type(8)));
typedef float f32x4 __attribute__((ext_vector_type(4)));
typedef unsigned short u16x8 __attribute__((ext_vector_type(8)));
typedef unsigned short u16x4 __attribute__((ext_vector_type(4)));

#define CD 768
#define NT 196
#define NB 128
#define T2 392
#define MROWS (NB*NT)   // 25088
#define BM 256
#define BN 256
#define NMT 98          // M tiles
#define NNT 3           // N tiles
#define TILES (NMT*NNT) // 294 per stream

__device__ __forceinline__ unsigned short f2bf(float f){
  unsigned u = __float_as_uint(f);
  u += 0x7fffu + ((u >> 16) & 1u);
  return (unsigned short)(u >> 16);
}
__device__ __forceinline__ float bf2f(unsigned short h){
  return __uint_as_float(((unsigned)h) << 16);
}
__device__ __forceinline__ float wave_reduce(float v){
  #pragma unroll
  for (int o = 32; o > 0; o >>= 1) v += __shfl_down(v, o, 64);
  return v;
}
__device__ __forceinline__ void gload16(const unsigned short* g, unsigned short* l){
  __builtin_amdgcn_global_load_lds(
      (const __attribute__((address_space(1))) unsigned int*)g,
      (__attribute__((address_space(3))) unsigned int*)l, 16, 0, 0);
}

// LDS-tiled transpose W1/W2 -> bf16 [n][k]; reads and writes coalesced.
__global__ __launch_bounds__(256) void prep_wt(const float* __restrict__ W1,
                        const float* __restrict__ W2,
                        unsigned short* __restrict__ W1t, unsigned short* __restrict__ W2t){
  __shared__ float tile[64][65];
  const float* src = blockIdx.z ? W2 : W1;
  unsigned short* dst = blockIdx.z ? W2t : W1t;
  int k0 = blockIdx.x*64, n0 = blockIdx.y*64;
  int tid = threadIdx.x;
  #pragma unroll
  for (int e = 0; e < 16; ++e){
    int idx = e*256 + tid;
    int r = idx >> 6, c = idx & 63;
    tile[r][c] = src[(size_t)(k0+r)*CD + n0 + c];
  }
  __syncthreads();
  #pragma unroll
  for (int e = 0; e < 16; ++e){
    int idx = e*256 + tid;
    int nr = idx >> 6, kc = idx & 63;
    dst[(size_t)(n0+nr)*CD + k0 + kc] = f2bf(tile[kc][nr]);
  }
}

// u3[k] = W3[k,:]@w5a ; u4s[j] = (W4[j,:]+W4[392+j,:])@w5b ; c = b3@w5a + b4@w5b + b5
__global__ void prep_u(const float* __restrict__ W3, const float* __restrict__ W4,
                       const float* __restrict__ W5, const float* __restrict__ b3,
                       const float* __restrict__ b4, const float* __restrict__ b5,
                       float* __restrict__ u3, float* __restrict__ u4s, float* __restrict__ cbuf){
  int wid = (blockIdx.x*blockDim.x + threadIdx.x) >> 6;
  int lane = threadIdx.x & 63;
  const float* w5a = W5;
  const float* w5b = W5 + CD;
  float s = 0.f;
  if (wid < CD){
    const float* row = W3 + (size_t)wid*CD;
    for (int k = lane; k < CD; k += 64) s += row[k]*w5a[k];
    s = wave_reduce(s);
    if (lane == 0) u3[wid] = s;
  } else if (wid < CD + T2){
    int j = wid - CD;
    const float* r0 = W4 + (size_t)j*784;
    const float* r1 = W4 + (size_t)(j+T2)*784;
    for (int e = lane; e < 784; e += 64) s += (r0[e]+r1[e])*w5b[e];
    s = wave_reduce(s);
    if (lane == 0) u4s[j] = s;
  } else if (wid == CD + T2){
    for (int k = lane; k < CD; k += 64) s += b3[k]*w5a[k];
    for (int e = lane; e < 784; e += 64) s += b4[e]*w5b[e];
    s = wave_reduce(s);
    if (lane == 0) cbuf[0] = s + b5[0];
  }
}

// t[b,d] := u3[d]  (plus two pad rows of zeros for 3-batch straddle atomics)
__global__ void init_t(const float* __restrict__ u3, float* __restrict__ t){
  int i = blockIdx.x*256 + threadIdx.x;
  if (i < (NB+2)*CD) t[i] = (i < NB*CD) ? u3[i % CD] : 0.f;
}

// fp32 -> bf16: converts x then y into one contiguous dst (xbf | ybf), grid-stride.
__global__ __launch_bounds__(256) void cvt2(const float* __restrict__ x,
                                            const float* __restrict__ y,
                                            unsigned short* __restrict__ dst){
  const int nv = MROWS*CD/8;   // vec8 count per stream
  for (int id = blockIdx.x*256 + threadIdx.x; id < 2*nv; id += gridDim.x*256){
    const float* s = (id < nv) ? x : y;
    int i = (id < nv) ? id : id - nv;
    float4 a = ((const float4*)s)[i*2];
    float4 b = ((const float4*)s)[i*2+1];
    u16x8 o = { f2bf(a.x), f2bf(a.y), f2bf(a.z), f2bf(a.w),
                f2bf(b.x), f2bf(b.y), f2bf(b.z), f2bf(b.w) };
    ((u16x8*)dst)[id] = o;
  }
}

// phi = relu((A@Bt^T + b)*g + be), fused t-accumulation. 256x256 tile, BK=64,
// 512 thr / 8 waves (2Mx4N, 128x64 per wave), double-buffered 128KB LDS.
// Per K-tile: 4 phases {ds_read quadrant; barrier; setprio+16 MFMA; barrier};
// 8-load stage burst for kt+1 at phase 0; single vmcnt(0) at end of phase 3
// (loads fly ~3.5 phases). mode<0: both streams one dispatch; else one stream.
__global__ __launch_bounds__(512, 2) void phi_gemm2(
    const unsigned short* __restrict__ Ax, const unsigned short* __restrict__ Ay,
    const unsigned short* __restrict__ Bx, const unsigned short* __restrict__ By,
    const float* __restrict__ biasX, const float* __restrict__ gamX, const float* __restrict__ betX,
    const float* __restrict__ biasY, const float* __restrict__ gamY, const float* __restrict__ betY,
    const float* __restrict__ u4s,
    unsigned short* __restrict__ Px, unsigned short* __restrict__ Py,
    float* __restrict__ t, int mode)
{
  __shared__ unsigned short As[2][BM*64];   // 64 KB
  __shared__ unsigned short Bs[2][BN*64];   // 64 KB

  const int tid  = threadIdx.x;
  const int lane = tid & 63;
  const int w    = tid >> 6;          // 0..7
  const int wm = w >> 2, wn = w & 3;  // 2M x 4N

  // bijective XCD swizzle (m204): works for any grid size
  const int nw = gridDim.x;
  const int q8 = nw >> 3, r8 = nw & 7;
  const int xcd = blockIdx.x & 7;
  const int tt  = blockIdx.x >> 3;
  int swz = (xcd < r8 ? xcd*(q8+1) : r8*(q8+1) + (xcd-r8)*q8) + tt;

  int s, rr;
  if (mode < 0){ s = swz >= TILES; rr = swz - s*TILES; }
  else         { s = mode; rr = swz; }
  const int bn = rr % NNT;   // fastest: consecutive blocks share the A panel
  const int bm = rr / NNT;

  const unsigned short* A   = s ? Ay : Ax;
  const unsigned short* Bt  = s ? By : Bx;
  const float* bias = s ? biasY : biasX;
  const float* gam  = s ? gamY  : gamX;
  const float* bet  = s ? betY  : betX;
  const float* u4c  = u4s + s*NT;
  unsigned short* phi = s ? Py : Px;

  // staging: chunk c covers rows c*64 + (tid>>3), phys 16B-slot p = tid&7;
  // phys slot p holds global slot (p - row)&7 (proven 0-conflict mod-8 swizzle)
  const int g0 = ((tid & 7) - (tid >> 3)) & 7;
  const unsigned short* aB = A  + (size_t)(bm*BM + (tid>>3))*CD + g0*8;
  const unsigned short* bB = Bt + (size_t)(bn*BN + (tid>>3))*CD + g0*8;

  const int fr = lane & 15, f = lane >> 4;
  const int ph0 = (f     + (fr & 7)) & 7;   // kk=0 read slot
  const int ph1 = (4 + f + (fr & 7)) & 7;   // kk=1 read slot

  f32x4 acc[8][4];
  #pragma unroll
  for (int mi = 0; mi < 8; ++mi)
    #pragma unroll
    for (int ni = 0; ni < 4; ++ni) acc[mi][ni] = f32x4{0.f,0.f,0.f,0.f};

#define STAGE(D, KT) { const int ko = (KT)*64;                         \
    _Pragma("unroll")                                                  \
    for (int cc = 0; cc < 4; ++cc){                                    \
      gload16(aB + (size_t)cc*64*CD + ko, &As[D][cc*4096 + tid*8]);    \
      gload16(bB + (size_t)cc*64*CD + ko, &Bs[D][cc*4096 + tid*8]); } }

#define RD_B(KK) {                                                     \
    _Pragma("unroll")                                                  \
    for (int ni = 0; ni < 4; ++ni)                                     \
      bq[ni] = *(const bf16x8*)(&cB[(wn*64 + ni*16 + fr)*64 + ((KK)?ph1:ph0)*8]); }

#define RD_A(MH, KK) {                                                 \
    _Pragma("unroll")                                                  \
    for (int m2 = 0; m2 < 4; ++m2)                                     \
      af[m2] = *(const bf16x8*)(&cA[(wm*128 + (MH)*64 + m2*16 + fr)*64 + ((KK)?ph1:ph0)*8]); }

#define MMA(MH) {                                                      \
    _Pragma("unroll")                                                  \
    for (int m2 = 0; m2 < 4; ++m2)                                     \
      _Pragma("unroll")                                                \
      for (int ni = 0; ni < 4; ++ni)                                   \
        acc[(MH)*4+m2][ni] = __builtin_amdgcn_mfma_f32_16x16x32_bf16(af[m2], bq[ni], acc[(MH)*4+m2][ni], 0, 0, 0); }

  STAGE(0, 0)
  asm volatile("s_waitcnt vmcnt(0)" ::: "memory");
  __builtin_amdgcn_s_barrier();

  #pragma unroll 1
  for (int kt = 0; kt < 12; ++kt){
    const int D = kt & 1;
    const unsigned short* cA = As[D];
    const unsigned short* cB = Bs[D];
    bf16x8 af[4], bq[4];

    // phase 0: stage next K-tile (into freed buffer), read bq(kk0)+af(mh0,kk0)
    if (kt < 11) STAGE(D^1, kt+1)
    RD_B(0) RD_A(0, 0)
    __builtin_amdgcn_s_barrier();
    __builtin_amdgcn_s_setprio(1); MMA(0) __builtin_amdgcn_s_setprio(0);
    __builtin_amdgcn_s_barrier();
    // phase 1: af(mh1,kk0), reuse bq
    RD_A(1, 0)
    __builtin_amdgcn_s_barrier();
    __builtin_amdgcn_s_setprio(1); MMA(1) __builtin_amdgcn_s_setprio(0);
    __builtin_amdgcn_s_barrier();
    // phase 2: bq(kk1)+af(mh0,kk1)
    RD_B(1) RD_A(0, 1)
    __builtin_amdgcn_s_barrier();
    __builtin_amdgcn_s_setprio(1); MMA(0) __builtin_amdgcn_s_setprio(0);
    __builtin_amdgcn_s_barrier();
    // phase 3: af(mh1,kk1); drain the stage burst (had ~3.5 phases to fly)
    RD_A(1, 1)
    __builtin_amdgcn_s_barrier();
    __builtin_amdgcn_s_setprio(1); MMA(1) __builtin_amdgcn_s_setprio(0);
    asm volatile("s_waitcnt vmcnt(0)" ::: "memory");
    __builtin_amdgcn_s_barrier();
  }
#undef MMA
#undef RD_A
#undef RD_B
#undef STAGE

  // epilogue: BN-affine + ReLU, bf16 phi store; t[b,col] += u4c[tok]*v
  // 256-row M-tile can straddle up to 3 batches -> 3 buckets (t has 2 pad rows)
  const int b_base = (bm*BM) / NT;
  #pragma unroll
  for (int ni = 0; ni < 4; ++ni){
    int col = bn*BN + wn*64 + ni*16 + fr;
    float bi = bias[col], ga = gam[col], be = bet[col];
    float cb0 = 0.f, cb1 = 0.f, cb2 = 0.f;
    #pragma unroll
    for (int mi = 0; mi < 8; ++mi){
      int r0 = bm*BM + wm*128 + mi*16 + f*4;
      #pragma unroll
      for (int j = 0; j < 4; ++j){
        int rg = r0 + j;
        float v = fmaxf((acc[mi][ni][j] + bi)*ga + be, 0.f);
        phi[(size_t)rg*CD + col] = f2bf(v);
        int b = rg / NT;
        int tok = rg - b*NT;
        float pv = u4c[tok]*v;
        int bk = b - b_base;
        cb0 += (bk == 0) ? pv : 0.f;
        cb1 += (bk == 1) ? pv : 0.f;
        cb2 += (bk == 2) ? pv : 0.f;
      }
    }
    cb0 += __shfl_xor(cb0, 16, 64); cb0 += __shfl_xor(cb0, 32, 64);
    cb1 += __shfl_xor(cb1, 16, 64); cb1 += __shfl_xor(cb1, 32, 64);
    cb2 += __shfl_xor(cb2, 16, 64); cb2 += __shfl_xor(cb2, 32, 64);
    if (lane < 16){
      atomicAdd(&t[(size_t)(b_base  )*CD + col], cb0);
      atomicAdd(&t[(size_t)(b_base+1)*CD + col], cb1);
      atomicAdd(&t[(size_t)(b_base+2)*CD + col], cb2);
    }
  }
}

// Fused: wx = phiX_row.t[b]+c, wy = phiY_row.t[b]+c, out = x*wx + y*wy.
template<bool USEBF>
__global__ __launch_bounds__(256) void comp_wout(
    const unsigned short* __restrict__ phiX, const unsigned short* __restrict__ phiY,
    const float* __restrict__ t, const float* __restrict__ cbuf,
    const float* __restrict__ x, const float* __restrict__ y,
    const unsigned short* __restrict__ xb, const unsigned short* __restrict__ yb,
    float* __restrict__ out)
{
  int gw   = (blockIdx.x*256 + threadIdx.x) >> 6;  // token 0..25087
  int lane = threadIdx.x & 63;
  int b = gw / NT;
  const unsigned short* px = phiX + (size_t)gw*CD;
  const unsigned short* py = phiY + (size_t)gw*CD;
  const float* tb = t + (size_t)b*CD;
  float s1 = 0.f, s2 = 0.f;
  #pragma unroll
  for (int it = 0; it < 3; ++it){
    int k = it*256 + lane*4;
    float4 tv = *(const float4*)(tb + k);
    u16x4 ux = *(const u16x4*)(px + k);
    u16x4 uy = *(const u16x4*)(py + k);
    s1 += bf2f(ux.x)*tv.x + bf2f(ux.y)*tv.y + bf2f(ux.z)*tv.z + bf2f(ux.w)*tv.w;
    s2 += bf2f(uy.x)*tv.x + bf2f(uy.y)*tv.y + bf2f(uy.z)*tv.z + bf2f(uy.w)*tv.w;
  }
  s1 = wave_reduce(s1);
  s2 = wave_reduce(s2);
  float cc = cbuf[0];
  float wx = __shfl(s1, 0, 64) + cc;
  float wy = __shfl(s2, 0, 64) + cc;
  float* orow = out + (size_t)gw*CD;
  #pragma unroll
  for (int it = 0; it < 3; ++it){
    int k = it*256 + lane*4;
    float4 xv, yv;
    if (USEBF){
      u16x4 a  = *(const u16x4*)(xb + (size_t)gw*CD + k);
      u16x4 c4 = *(const u16x4*)(yb + (size_t)gw*CD + k);
      xv = float4{bf2f(a.x), bf2f(a.y), bf2f(a.z), bf2f(a.w)};
      yv = float4{bf2f(c4.x), bf2f(c4.y), bf2f(c4.z), bf2f(c4.w)};
    } else {
      xv = *(const float4*)(x + (size_t)gw*CD + k);
      yv = *(const float4*)(y + (size_t)gw*CD + k);
    }
    float4 o;
    o.x = xv.x*wx + yv.x*wy;
    o.y = xv.y*wx + yv.y*wy;
    o.z = xv.z*wx + yv.z*wy;
    o.w = xv.w*wx + yv.w*wy;
    *(float4*)(orow + k) = o;
  }
}

extern "C" void kernel_launch(void* const* d_in, const int* in_sizes, int n_in,
                              void* d_out, int out_size, void* d_ws, size_t ws_size,
                              hipStream_t stream){
  const float* x  = (const float*)d_in[0];
  const float* y  = (const float*)d_in[1];
  const float* W1 = (const float*)d_in[2];
  const float* b1 = (const float*)d_in[3];
  const float* g1 = (const float*)d_in[4];
  const float* be1= (const float*)d_in[5];
  const float* W2 = (const float*)d_in[6];
  const float* b2 = (const float*)d_in[7];
  const float* g2 = (const float*)d_in[8];
  const float* be2= (const float*)d_in[9];
  const float* W3 = (const float*)d_in[10];
  const float* b3 = (const float*)d_in[11];
  const float* W4 = (const float*)d_in[12];
  const float* b4 = (const float*)d_in[13];
  const float* W5 = (const float*)d_in[14];
  const float* b5 = (const float*)d_in[15];
  float* out = (float*)d_out;

  const size_t BIGE = (size_t)MROWS*CD;          // elements per big bf16 buffer
  const size_t smallF = CD + T2 + 4 + (size_t)(NB+2)*CD;
  const size_t need4 = (2*(size_t)CD*CD + 4*BIGE)*2 + smallF*4 + 256;
  const bool big = (ws_size >= need4);

  unsigned short* W1t = (unsigned short*)d_ws;
  unsigned short* W2t = W1t + CD*CD;
  unsigned short* Sx  = W2t + CD*CD;     // xbf  (small layout: later phiY)
  unsigned short* Sy  = Sx + BIGE;       // ybf
  unsigned short* Px, * Py;
  float* smalls;
  if (big){
    Px = Sy + BIGE;                      // phiX
    Py = Px + BIGE;                      // phiY
    smalls = (float*)(Py + BIGE);
  } else {
    Px = Sy + BIGE;                      // phiX
    Py = Sx;                             // phiY overwrites xbf
    smalls = (float*)(Px + BIGE);
  }
  float* u3   = smalls;                  // 768
  float* u4s  = u3 + CD;                 // 392
  float* cbuf = u4s + T2;                // 1 (+pad)
  float* t    = cbuf + 4;                // (128+2)*768

  prep_wt<<<dim3(12,12,2), 256, 0, stream>>>(W1, W2, W1t, W2t);
  prep_u<<<(CD + T2 + 4)/4, 256, 0, stream>>>(W3, W4, W5, b3, b4, b5, u3, u4s, cbuf);
  init_t<<<((NB+2)*CD + 255)/256, 256, 0, stream>>>(u3, t);

  cvt2<<<2048, 256, 0, stream>>>(x, y, Sx);   // fills Sx=xbf, Sy=ybf (contiguous)

  if (big){
    // both streams in one dispatch: 588 blocks x 512 threads
    phi_gemm2<<<2*TILES, 512, 0, stream>>>(Sx, Sy, W1t, W2t,
        b1, g1, be1, b2, g2, be2, u4s, Px, Py, t, -1);
    comp_wout<true><<<MROWS/4, 256, 0, stream>>>(Px, Py, t, cbuf, x, y, Sx, Sy, out);
  } else {
    // small ws: phiY aliases xbf, so streams must serialize
    phi_gemm2<<<TILES, 512, 0, stream>>>(Sx, Sy, W1t, W2t,
        b1, g1, be1, b2, g2, be2, u4s, Px, Py, t, 0);
    phi_gemm2<<<TILES, 512, 0, stream>>>(Sx, Sy, W1t, W2t,
        b1, g1, be1, b2, g2, be2, u4s, Px, Py, t, 1);
    comp_wout<false><<<MROWS/4, 256, 0, stream>>>(Px, Py, t, cbuf, x, y, Sx, Sy, out);
  }
}

// Round 8
// 179.010 us; speedup vs baseline: 1.4015x; 1.4015x over previous
//
#include <hip/hip_runtime.h>

typedef __bf16 bf16_t;
typedef bf16_t bf16x8 __attribute__((ext_vector_type(8)));
typedef float f32x4 __attribute__((ext_vector_type(4)));
typedef float f32x16 __attribute__((ext_vector_type(16)));
typedef unsigned short u16x8 __attribute__((ext_vector_type(8)));
typedef unsigned short u16x4 __attribute__((ext_vector_type(4)));

#define CD 768
#define NT 196
#define NB 128
#define T2 392
#define MROWS (NB*NT)   // 25088
#define NTILE 1176      // (MROWS/128) * (CD/128)

__device__ __forceinline__ unsigned short f2bf(float f){
  unsigned u = __float_as_uint(f);
  u += 0x7fffu + ((u >> 16) & 1u);
  return (unsigned short)(u >> 16);
}
__device__ __forceinline__ float bf2f(unsigned short h){
  return __uint_as_float(((unsigned)h) << 16);
}
__device__ __forceinline__ float wave_reduce(float v){
  #pragma unroll
  for (int o = 32; o > 0; o >>= 1) v += __shfl_down(v, o, 64);
  return v;
}
__device__ __forceinline__ void gload16(const unsigned short* g, unsigned short* l){
  __builtin_amdgcn_global_load_lds(
      (const __attribute__((address_space(1))) unsigned int*)g,
      (__attribute__((address_space(3))) unsigned int*)l, 16, 0, 0);
}

// LDS-tiled transpose W1/W2 -> bf16 [n][k]; reads and writes coalesced.
__global__ __launch_bounds__(256) void prep_wt(const float* __restrict__ W1,
                        const float* __restrict__ W2,
                        unsigned short* __restrict__ W1t, unsigned short* __restrict__ W2t){
  __shared__ float tile[64][65];
  const float* src = blockIdx.z ? W2 : W1;
  unsigned short* dst = blockIdx.z ? W2t : W1t;
  int k0 = blockIdx.x*64, n0 = blockIdx.y*64;
  int tid = threadIdx.x;
  #pragma unroll
  for (int e = 0; e < 16; ++e){
    int idx = e*256 + tid;
    int r = idx >> 6, c = idx & 63;
    tile[r][c] = src[(size_t)(k0+r)*CD + n0 + c];
  }
  __syncthreads();
  #pragma unroll
  for (int e = 0; e < 16; ++e){
    int idx = e*256 + tid;
    int nr = idx >> 6, kc = idx & 63;
    dst[(size_t)(n0+nr)*CD + k0 + kc] = f2bf(tile[kc][nr]);
  }
}

// u3[k] = W3[k,:]@w5a ; u4s[j] = (W4[j,:]+W4[392+j,:])@w5b ; c = b3@w5a + b4@w5b + b5
__global__ void prep_u(const float* __restrict__ W3, const float* __restrict__ W4,
                       const float* __restrict__ W5, const float* __restrict__ b3,
                       const float* __restrict__ b4, const float* __restrict__ b5,
                       float* __restrict__ u3, float* __restrict__ u4s, float* __restrict__ cbuf){
  int wid = (blockIdx.x*blockDim.x + threadIdx.x) >> 6;
  int lane = threadIdx.x & 63;
  const float* w5a = W5;
  const float* w5b = W5 + CD;
  float s = 0.f;
  if (wid < CD){
    const float* row = W3 + (size_t)wid*CD;
    for (int k = lane; k < CD; k += 64) s += row[k]*w5a[k];
    s = wave_reduce(s);
    if (lane == 0) u3[wid] = s;
  } else if (wid < CD + T2){
    int j = wid - CD;
    const float* r0 = W4 + (size_t)j*784;
    const float* r1 = W4 + (size_t)(j+T2)*784;
    for (int e = lane; e < 784; e += 64) s += (r0[e]+r1[e])*w5b[e];
    s = wave_reduce(s);
    if (lane == 0) u4s[j] = s;
  } else if (wid == CD + T2){
    for (int k = lane; k < CD; k += 64) s += b3[k]*w5a[k];
    for (int e = lane; e < 784; e += 64) s += b4[e]*w5b[e];
    s = wave_reduce(s);
    if (lane == 0) cbuf[0] = s + b5[0];
  }
}

// t[b,d] := u3[d]  (plus pad rows of zeros for straddle atomics)
__global__ void init_t(const float* __restrict__ u3, float* __restrict__ t){
  int i = blockIdx.x*256 + threadIdx.x;
  if (i < (NB+2)*CD) t[i] = (i < NB*CD) ? u3[i % CD] : 0.f;
}

// fp32 -> bf16: converts x then y into one contiguous dst (xbf | ybf), grid-stride.
__global__ __launch_bounds__(256) void cvt2(const float* __restrict__ x,
                                            const float* __restrict__ y,
                                            unsigned short* __restrict__ dst){
  const int nv = MROWS*CD/8;   // vec8 count per stream
  for (int id = blockIdx.x*256 + threadIdx.x; id < 2*nv; id += gridDim.x*256){
    const float* s = (id < nv) ? x : y;
    int i = (id < nv) ? id : id - nv;
    float4 a = ((const float4*)s)[i*2];
    float4 b = ((const float4*)s)[i*2+1];
    u16x8 o = { f2bf(a.x), f2bf(a.y), f2bf(a.z), f2bf(a.w),
                f2bf(b.x), f2bf(b.y), f2bf(b.z), f2bf(b.w) };
    ((u16x8*)dst)[id] = o;
  }
}

// phi = relu((A@Bt^T + b)*g + be), both streams one dispatch (mode<0) or one
// stream (mode=0/1). R6-verified schedule: 128x128 tile, BK=64 single-buffer
// (32KB LDS, 4 blocks/CU), stage -> sync -> compute -> sync, additive mod-8
// swizzle. THIS ROUND: MFMA 32x32x16 (2x FLOP/inst, better store coalescing).
__global__ __launch_bounds__(256, 4) void phi_gemm2(
    const unsigned short* __restrict__ Ax, const unsigned short* __restrict__ Ay,
    const unsigned short* __restrict__ Bx, const unsigned short* __restrict__ By,
    const float* __restrict__ biasX, const float* __restrict__ gamX, const float* __restrict__ betX,
    const float* __restrict__ biasY, const float* __restrict__ gamY, const float* __restrict__ betY,
    const float* __restrict__ u4s,
    unsigned short* __restrict__ Px, unsigned short* __restrict__ Py,
    float* __restrict__ t, int mode)
{
  __shared__ unsigned short As[128*64];
  __shared__ unsigned short Bs[128*64];

  const int tid  = threadIdx.x;
  const int lane = tid & 63;
  const int w    = tid >> 6;
  const int wr = w >> 1, wc = w & 1;

  // XCD-bijective chunked swizzle; bn-fastest within each XCD chunk
  const int chunk = gridDim.x >> 3;
  int orig = blockIdx.x;
  int swz  = (orig & 7)*chunk + (orig >> 3);
  int s, r;
  if (mode < 0){ s = swz >= NTILE; r = swz - s*NTILE; }
  else         { s = mode; r = swz; }
  const int bn = r % 6;
  const int bm = r / 6;

  const unsigned short* A   = s ? Ay : Ax;
  const unsigned short* Bt  = s ? By : Bx;
  const float* bias = s ? biasY : biasX;
  const float* gam  = s ? gamY  : gamX;
  const float* bet  = s ? betY  : betX;
  const float* u4c  = u4s + s*NT;
  unsigned short* phi = s ? Py : Px;

  // staging (verified 0 conflicts): wave w covers rows w*32 + c*8 + srow;
  // phys 16B-slot p of a 128B row holds global slot (p - row)&7
  const int srow = lane >> 3;
  const int p    = lane & 7;
  const int g0   = (p - srow) & 7;
  const unsigned short* a0 = A  + (size_t)(bm*128 + w*32 + srow)*CD + g0*8;
  const unsigned short* b0 = Bt + (size_t)(bn*128 + w*32 + srow)*CD + g0*8;
  unsigned short* al = &As[(w*32)*64];
  unsigned short* bl = &Bs[(w*32)*64];

  // 32x32x16 fragment addressing: row/col = lane&31, k = (lane>>5)*8 + i
  const int l31 = lane & 31;
  const int lh  = lane >> 5;
  const int r7  = l31 & 7;

  f32x16 acc[2][2] = {};

  #pragma unroll 1
  for (int kt = 0; kt < 12; ++kt){
    const int ko = kt*64;
    #pragma unroll
    for (int c = 0; c < 4; ++c){
      gload16(a0 + (size_t)c*8*CD + ko, al + c*512);
      gload16(b0 + (size_t)c*8*CD + ko, bl + c*512);
    }
    __syncthreads();   // drains vmcnt -> staged data visible
    #pragma unroll
    for (int ks = 0; ks < 4; ++ks){
      const int phys = ((ks*2 + lh) + r7) & 7;
      bf16x8 af[2], bq[2];
      #pragma unroll
      for (int mi = 0; mi < 2; ++mi){
        int rr = wr*64 + mi*32 + l31;
        af[mi] = *(const bf16x8*)(&As[rr*64 + phys*8]);
      }
      #pragma unroll
      for (int nj = 0; nj < 2; ++nj){
        int cc = wc*64 + nj*32 + l31;
        bq[nj] = *(const bf16x8*)(&Bs[cc*64 + phys*8]);
      }
      #pragma unroll
      for (int mi = 0; mi < 2; ++mi)
        #pragma unroll
        for (int nj = 0; nj < 2; ++nj)
          acc[mi][nj] = __builtin_amdgcn_mfma_f32_32x32x16_bf16(af[mi], bq[nj], acc[mi][nj], 0, 0, 0);
    }
    if (kt < 11) __syncthreads();   // reads done before next stage overwrites
  }

  // epilogue: BN-affine + ReLU, bf16 phi store; t[b,col] += u4c[tok]*v.
  // C/D layout: col = lane&31 (+32*nj+64*wc), row = (reg&3)+8*(reg>>2)+4*lh.
  const int b_base = (bm*128) / NT;
  int  col0 = bn*128 + wc*64 + l31;
  float bi0 = bias[col0],    ga0 = gam[col0],    be0 = bet[col0];
  float bi1 = bias[col0+32], ga1 = gam[col0+32], be1 = bet[col0+32];
  float cb[2][2] = {{0.f,0.f},{0.f,0.f}};   // [nj][batch bucket]
  #pragma unroll
  for (int mi = 0; mi < 2; ++mi){
    #pragma unroll
    for (int reg = 0; reg < 16; ++reg){
      int rg  = bm*128 + wr*64 + mi*32 + (reg & 3) + 8*(reg >> 2) + 4*lh;
      int b   = rg / NT;
      int tok = rg - b*NT;
      float uw = u4c[tok];
      int bk  = b - b_base;
      #pragma unroll
      for (int nj = 0; nj < 2; ++nj){
        float v = (nj ? (acc[mi][nj][reg] + bi1)*ga1 + be1
                      : (acc[mi][nj][reg] + bi0)*ga0 + be0);
        v = fmaxf(v, 0.f);
        phi[(size_t)rg*CD + col0 + nj*32] = f2bf(v);
        float pv = uw*v;
        cb[nj][0] += (bk == 0) ? pv : 0.f;
        cb[nj][1] += (bk == 1) ? pv : 0.f;
      }
    }
  }
  #pragma unroll
  for (int nj = 0; nj < 2; ++nj){
    cb[nj][0] += __shfl_xor(cb[nj][0], 32, 64);
    cb[nj][1] += __shfl_xor(cb[nj][1], 32, 64);
  }
  if (lane < 32){
    atomicAdd(&t[(size_t)(b_base  )*CD + col0   ], cb[0][0]);
    atomicAdd(&t[(size_t)(b_base+1)*CD + col0   ], cb[0][1]);
    atomicAdd(&t[(size_t)(b_base  )*CD + col0+32], cb[1][0]);
    atomicAdd(&t[(size_t)(b_base+1)*CD + col0+32], cb[1][1]);
  }
}

// Fused: wx = phiX_row.t[b]+c, wy = phiY_row.t[b]+c, out = x*wx + y*wy.
template<bool USEBF>
__global__ __launch_bounds__(256) void comp_wout(
    const unsigned short* __restrict__ phiX, const unsigned short* __restrict__ phiY,
    const float* __restrict__ t, const float* __restrict__ cbuf,
    const float* __restrict__ x, const float* __restrict__ y,
    const unsigned short* __restrict__ xb, const unsigned short* __restrict__ yb,
    float* __restrict__ out)
{
  int gw   = (blockIdx.x*256 + threadIdx.x) >> 6;  // token 0..25087
  int lane = threadIdx.x & 63;
  int b = gw / NT;
  const unsigned short* px = phiX + (size_t)gw*CD;
  const unsigned short* py = phiY + (size_t)gw*CD;
  const float* tb = t + (size_t)b*CD;
  float s1 = 0.f, s2 = 0.f;
  #pragma unroll
  for (int it = 0; it < 3; ++it){
    int k = it*256 + lane*4;
    float4 tv = *(const float4*)(tb + k);
    u16x4 ux = *(const u16x4*)(px + k);
    u16x4 uy = *(const u16x4*)(py + k);
    s1 += bf2f(ux.x)*tv.x + bf2f(ux.y)*tv.y + bf2f(ux.z)*tv.z + bf2f(ux.w)*tv.w;
    s2 += bf2f(uy.x)*tv.x + bf2f(uy.y)*tv.y + bf2f(uy.z)*tv.z + bf2f(uy.w)*tv.w;
  }
  s1 = wave_reduce(s1);
  s2 = wave_reduce(s2);
  float cc = cbuf[0];
  float wx = __shfl(s1, 0, 64) + cc;
  float wy = __shfl(s2, 0, 64) + cc;
  float* orow = out + (size_t)gw*CD;
  #pragma unroll
  for (int it = 0; it < 3; ++it){
    int k = it*256 + lane*4;
    float4 xv, yv;
    if (USEBF){
      u16x4 a  = *(const u16x4*)(xb + (size_t)gw*CD + k);
      u16x4 c4 = *(const u16x4*)(yb + (size_t)gw*CD + k);
      xv = float4{bf2f(a.x), bf2f(a.y), bf2f(a.z), bf2f(a.w)};
      yv = float4{bf2f(c4.x), bf2f(c4.y), bf2f(c4.z), bf2f(c4.w)};
    } else {
      xv = *(const float4*)(x + (size_t)gw*CD + k);
      yv = *(const float4*)(y + (size_t)gw*CD + k);
    }
    float4 o;
    o.x = xv.x*wx + yv.x*wy;
    o.y = xv.y*wx + yv.y*wy;
    o.z = xv.z*wx + yv.z*wy;
    o.w = xv.w*wx + yv.w*wy;
    *(float4*)(orow + k) = o;
  }
}

extern "C" void kernel_launch(void* const* d_in, const int* in_sizes, int n_in,
                              void* d_out, int out_size, void* d_ws, size_t ws_size,
                              hipStream_t stream){
  const float* x  = (const float*)d_in[0];
  const float* y  = (const float*)d_in[1];
  const float* W1 = (const float*)d_in[2];
  const float* b1 = (const float*)d_in[3];
  const float* g1 = (const float*)d_in[4];
  const float* be1= (const float*)d_in[5];
  const float* W2 = (const float*)d_in[6];
  const float* b2 = (const float*)d_in[7];
  const float* g2 = (const float*)d_in[8];
  const float* be2= (const float*)d_in[9];
  const float* W3 = (const float*)d_in[10];
  const float* b3 = (const float*)d_in[11];
  const float* W4 = (const float*)d_in[12];
  const float* b4 = (const float*)d_in[13];
  const float* W5 = (const float*)d_in[14];
  const float* b5 = (const float*)d_in[15];
  float* out = (float*)d_out;

  const size_t BIGE = (size_t)MROWS*CD;          // elements per big bf16 buffer
  const size_t smallF = CD + T2 + 4 + (size_t)(NB+2)*CD;
  const size_t need4 = (2*(size_t)CD*CD + 4*BIGE)*2 + smallF*4 + 256;
  const bool big = (ws_size >= need4);

  unsigned short* W1t = (unsigned short*)d_ws;
  unsigned short* W2t = W1t + CD*CD;
  unsigned short* Sx  = W2t + CD*CD;     // xbf  (small layout: later phiY)
  unsigned short* Sy  = Sx + BIGE;       // ybf
  unsigned short* Px, * Py;
  float* smalls;
  if (big){
    Px = Sy + BIGE;                      // phiX
    Py = Px + BIGE;                      // phiY
    smalls = (float*)(Py + BIGE);
  } else {
    Px = Sy + BIGE;                      // phiX
    Py = Sx;                             // phiY overwrites xbf
    smalls = (float*)(Px + BIGE);
  }
  float* u3   = smalls;                  // 768
  float* u4s  = u3 + CD;                 // 392
  float* cbuf = u4s + T2;                // 1 (+pad)
  float* t    = cbuf + 4;                // (128+2)*768

  prep_wt<<<dim3(12,12,2), 256, 0, stream>>>(W1, W2, W1t, W2t);
  prep_u<<<(CD + T2 + 4)/4, 256, 0, stream>>>(W3, W4, W5, b3, b4, b5, u3, u4s, cbuf);
  init_t<<<((NB+2)*CD + 255)/256, 256, 0, stream>>>(u3, t);

  cvt2<<<2048, 256, 0, stream>>>(x, y, Sx);   // fills Sx=xbf, Sy=ybf (contiguous)

  if (big){
    // both streams in one dispatch: 2352 = 8 * 294 blocks
    phi_gemm2<<<2*NTILE, 256, 0, stream>>>(Sx, Sy, W1t, W2t,
        b1, g1, be1, b2, g2, be2, u4s, Px, Py, t, -1);
    comp_wout<true><<<MROWS/4, 256, 0, stream>>>(Px, Py, t, cbuf, x, y, Sx, Sy, out);
  } else {
    // small ws: phiY aliases xbf, so streams must serialize
    phi_gemm2<<<NTILE, 256, 0, stream>>>(Sx, Sy, W1t, W2t,
        b1, g1, be1, b2, g2, be2, u4s, Px, Py, t, 0);
    phi_gemm2<<<NTILE, 256, 0, stream>>>(Sx, Sy, W1t, W2t,
        b1, g1, be1, b2, g2, be2, u4s, Px, Py, t, 1);
    comp_wout<false><<<MROWS/4, 256, 0, stream>>>(Px, Py, t, cbuf, x, y, Sx, Sy, out);
  }
}